// Round 8
// baseline (706.831 us; speedup 1.0000x reference)
//
#include <hip/hip_runtime.h>
#include <hip/hip_bf16.h>

// Correctness contract (exact path verified absmax=0 through R7):
//   xc   = sequential __fmaf_rn chain over d=0..63 ascending
//   x2,c2= numpy pairwise scalar 8-accumulator scheme
//   dist = fl(fl(x2 - 2*xc) + c2), argmin first-occurrence
//
// R-this-round (precision-elastic fast pass):
//   3-product split-bf16 tripled matrix work (103 vs 34 GFLOP) to buy
//   MARGIN=5e-3. Corrected cycle model: that 3x IS the measured 42-44us
//   MfmaUtil floor. Replaced with 1-product bf16 + RIGOROUS dynamic margin:
//     s_k = c2_k + sum fl32( bf16(x) * bf16(-2c) ),  u_bf16 = 2^-8
//     |s_k - (d_k - x2)| <= (2^-7+2^-16)*2*||x||*||c|| + (acc+ref rounding)
//     M(token,m) = 0.036*sqrt(x2*c2max_m) + 0.01  >= 2*eps  (>=15% slack)
//   Near-ties (v2-v1 <= M) -> pass-2: 1-product re-pass collects
//   {k: s <= v1_run + M} (superset of true candidates), then bit-exact
//   chain eval, lex-(val,k) reduce. Flag rate ~25-30% (gap scale ~8),
//   candidate sets ~1-2 -> pass-2 stays cheap. Main loop: 4 MFMA + 2
//   ds_read per tile (was 12+4), bpack 2MB (was 4), LDS 22KB -> 7 blk/CU.
//   Skeleton = R3 measured-best (16 phases x 4 tiles, dbuf stage,
//   2048 x 256thr, launch_bounds(256,4), immediate min-track).
#pragma clang fp contract(off)

#define NSUB 16
#define CBK  1024
#define SDIM 64
#define EMB  1024
#define NTOK 16384
#define TOKB 128
#define MCOEF  0.036f
#define MFLOOR 0.01f

typedef __attribute__((ext_vector_type(8))) short bf16x8;
typedef __attribute__((ext_vector_type(4))) float f32x4;

__device__ __forceinline__ float fmul(float a, float b) { return __fmul_rn(a, b); }
__device__ __forceinline__ float fadd(float a, float b) { return __fadd_rn(a, b); }
__device__ __forceinline__ float fsub(float a, float b) { return __fsub_rn(a, b); }

__device__ __forceinline__ short bf16rn(float v) {
    __hip_bfloat16 h = __float2bfloat16(v);   // RN
    return *(short*)&h;
}

// numpy pairwise replica (scalar 8-accumulator, n=64), contiguous.
__device__ __forceinline__ float np_sq64(const float* v) {
    float r[8];
    #pragma unroll
    for (int j = 0; j < 8; ++j) r[j] = fmul(v[j], v[j]);
    #pragma unroll
    for (int b = 1; b < 8; ++b) {
        #pragma unroll
        for (int j = 0; j < 8; ++j)
            r[j] = fadd(r[j], fmul(v[b * 8 + j], v[b * 8 + j]));
    }
    return fadd(fadd(fadd(r[0], r[1]), fadd(r[2], r[3])),
                fadd(fadd(r[4], r[5]), fadd(r[6], r[7])));
}

// async global->LDS, 16B per lane; dest = wave-uniform base + lane*16.
typedef const __attribute__((address_space(1))) unsigned int gu32;
typedef __attribute__((address_space(3))) unsigned int lu32;
__device__ __forceinline__ void stage16(const void* g, void* l) {
    __builtin_amdgcn_global_load_lds((gu32*)g, (lu32*)l, 16, 0, 0);
}

// ---- prep: pack bf16(-2*codebook) into MFMA B-fragment layout + C2 ----
// bpack layout: [m][tc=64][c=2][lane=64][j=8] bf16  (2 MB)
__global__ __launch_bounds__(256)
void prep_kernel(const float* __restrict__ cb,
                 unsigned short* __restrict__ bpack,
                 float* __restrict__ c2g)
{
    const int bx = blockIdx.x;   // 0..31
    const int m  = blockIdx.y;   // 0..15
    const int t  = threadIdx.x;
    const int w  = t >> 6, l = t & 63;
    const int tc = bx * 2 + (w & 1);           // tile-col 0..63
    const int c  = w >> 1;                     // c-half 0..1
    const int cw = tc * 16 + (l & 15);
    const int dq = (l >> 4) * 8;

    {
        const float* src = cb + ((size_t)m * CBK + cw) * SDIM + c * 32 + dq;
        bf16x8 hv;
        #pragma unroll
        for (int j = 0; j < 8; ++j)
            hv[j] = bf16rn(-2.0f * src[j]);    // -2x exact in fp32, then RN
        size_t base = (((size_t)(m * 64 + tc) * 2 + c)) * 512 + (size_t)l * 8;
        *(bf16x8*)(bpack + base) = hv;         // 16B vector stores, coalesced
    }
    if (t < 32) {
        const int row = bx * 32 + t;
        c2g[m * CBK + row] = np_sq64(cb + ((size_t)m * CBK + row) * SDIM);
    }
}

// ---- transpose: ws indices [m][NTOK] -> iout [NTOK][16], full-line writes ----
__global__ __launch_bounds__(256)
void idx_transpose_kernel(const float* __restrict__ iws,
                          float* __restrict__ iout)
{
    const int tok = blockIdx.x * 256 + threadIdx.x;
    float v[NSUB];
    #pragma unroll
    for (int m = 0; m < NSUB; ++m)
        v[m] = iws[(size_t)m * NTOK + tok];      // coalesced per-m reads
    float* dst = iout + (size_t)tok * NSUB;      // 64B line per thread
    #pragma unroll
    for (int c = 0; c < 4; ++c)
        *(f32x4*)(dst + c * 4) = *(f32x4*)(v + c * 4);
}

// ---- main: 1-product bf16 fast pass + candidate-set exact rescan ----
__global__ __launch_bounds__(256, 4)
void pq_mfma_kernel(const float* __restrict__ emb,
                    const float* __restrict__ cb,
                    const unsigned short* __restrict__ bpack,
                    const float* __restrict__ c2g,
                    float* __restrict__ qout,
                    float* __restrict__ iws)
{
    __shared__ __align__(16) unsigned short bs[2][4 * 1024];  // 2 x 8KB B stage
    __shared__ float C2s[CBK];              // 4 KB replica ||c||^2
    __shared__ float x2s[TOKB];             // per-token ||x||^2 (margin input)
    __shared__ int   bestk_s[TOKB];
    __shared__ int   flag_s[TOKB];
    __shared__ int   cnt_s;
    __shared__ int   c2maxb;                // float-bits max of c2 (c2>0)

    // XCD-aware decomposition: XCD (rank%8) only sees m in {rank%8, rank%8+8}
    const int rank = blockIdx.x;
    const int m    = rank & 15;
    const int tok0 = (rank >> 4) * TOKB;

    const int t = threadIdx.x, w = t >> 6, l = t & 63;
    const int ln15 = l & 15, q = l >> 4;

    if (t == 0) { cnt_s = 0; c2maxb = 0; }
    f32x4 c2quad = *(const f32x4*)(c2g + m * CBK + t * 4);
    *(f32x4*)(C2s + t * 4) = c2quad;
    float c2lm = fmaxf(fmaxf(c2quad[0], c2quad[1]), fmaxf(c2quad[2], c2quad[3]));

    const unsigned short* gB = bpack + (size_t)m * 64 * 1024;  // 128KB slice

    // stage phase 0 (tiles 0..3, 8KB)
    {
        const unsigned short* src = gB + t * 8;
        #pragma unroll
        for (int j = 0; j < 2; ++j)
            stage16(src + j * 2048, &bs[0][j * 2048 + t * 8]);
    }

    // x fragments (A-operand: row=lane&15, k=(lane>>4)*8+j), single bf16 RN;
    // per-token x2 partial (16 dims/lane) -> xor-reduce over q-lanes.
    bf16x8 xh[2][2];
    #pragma unroll
    for (int r = 0; r < 2; ++r) {
        const int tok = tok0 + w * 32 + r * 16 + ln15;
        float x2p = 0.f;
        #pragma unroll
        for (int c = 0; c < 2; ++c) {
            const float* src = emb + (size_t)tok * EMB + m * SDIM + c * 32 + q * 8;
            float4 v0 = *(const float4*)(src);
            float4 v1 = *(const float4*)(src + 4);
            float vv[8] = {v0.x,v0.y,v0.z,v0.w,v1.x,v1.y,v1.z,v1.w};
            #pragma unroll
            for (int j = 0; j < 8; ++j) {
                xh[r][c][j] = bf16rn(vv[j]);
                x2p += vv[j] * vv[j];
            }
        }
        x2p += __shfl_xor(x2p, 16);
        x2p += __shfl_xor(x2p, 32);
        if (l < 16) x2s[w * 32 + r * 16 + l] = x2p;   // lane q==0 writes
    }

    float v1t[2][4], v2t[2][4]; int k1t[2][4];
    #pragma unroll
    for (int r = 0; r < 2; ++r)
        #pragma unroll
        for (int g = 0; g < 4; ++g) { v1t[r][g] = 3.4e38f; v2t[r][g] = 3.4e38f; k1t[r][g] = 0; }

    __syncthreads();   // C2s/x2s/init visible + phase-0 stage complete
    atomicMax(&c2maxb, __float_as_int(c2lm));   // read only after loop barriers

    // 16 phases x 4 tiles; stage next phase while computing current.
    for (int ph = 0; ph < 16; ++ph) {
        const int buf = ph & 1;
        if (ph < 15) {
            const unsigned short* src = gB + (size_t)(ph + 1) * 4096 + t * 8;
            #pragma unroll
            for (int j = 0; j < 2; ++j)
                stage16(src + j * 2048, &bs[buf ^ 1][j * 2048 + t * 8]);
        }
        #pragma unroll
        for (int j = 0; j < 4; ++j) {
            const int tc = ph * 4 + j;
            const unsigned short* bp = &bs[buf][j * 1024 + l * 8];
            bf16x8 B0 = *(const bf16x8*)(bp);
            bf16x8 B1 = *(const bf16x8*)(bp + 512);
            const int kk = tc * 16 + ln15;
            const float c2v = C2s[kk];
            f32x4 a0 = {c2v, c2v, c2v, c2v};
            f32x4 a1 = {c2v, c2v, c2v, c2v};
            a0 = __builtin_amdgcn_mfma_f32_16x16x32_bf16(xh[0][0], B0, a0, 0, 0, 0);
            a1 = __builtin_amdgcn_mfma_f32_16x16x32_bf16(xh[1][0], B0, a1, 0, 0, 0);
            a0 = __builtin_amdgcn_mfma_f32_16x16x32_bf16(xh[0][1], B1, a0, 0, 0, 0);
            a1 = __builtin_amdgcn_mfma_f32_16x16x32_bf16(xh[1][1], B1, a1, 0, 0, 0);
            #pragma unroll
            for (int g = 0; g < 4; ++g) {
                float s0 = a0[g];
                v2t[0][g] = fminf(v2t[0][g], fmaxf(s0, v1t[0][g]));
                bool lt0 = s0 < v1t[0][g];
                v1t[0][g] = lt0 ? s0 : v1t[0][g];
                k1t[0][g] = lt0 ? kk : k1t[0][g];
                float s1 = a1[g];
                v2t[1][g] = fminf(v2t[1][g], fmaxf(s1, v1t[1][g]));
                bool lt1 = s1 < v1t[1][g];
                v1t[1][g] = lt1 ? s1 : v1t[1][g];
                k1t[1][g] = lt1 ? kk : k1t[1][g];
            }
        }
        __syncthreads();
    }

    const float c2mx = __int_as_float(c2maxb);

    // merge top-2 across the 16 lanes sharing each token (C/D row = q*4+g)
    #pragma unroll
    for (int r = 0; r < 2; ++r) {
        #pragma unroll
        for (int g = 0; g < 4; ++g) {
            float v1 = v1t[r][g], v2 = v2t[r][g]; int k1 = k1t[r][g];
            #pragma unroll
            for (int mask = 1; mask < 16; mask <<= 1) {
                float ov1 = __shfl_xor(v1, mask);
                float ov2 = __shfl_xor(v2, mask);
                int   ok1 = __shfl_xor(k1, mask);
                if (ov1 < v1 || (ov1 == v1 && ok1 < k1)) {
                    v2 = fminf(v1, ov2);
                    v1 = ov1; k1 = ok1;
                } else {
                    v2 = fminf(v2, ov1);
                }
            }
            if (ln15 == 0) {
                const int token = w * 32 + r * 16 + q * 4 + g;
                const float Mtok = MCOEF * sqrtf(x2s[token] * c2mx) + MFLOOR;
                if (v2 - v1 <= Mtok) {
                    int slot = atomicAdd(&cnt_s, 1);
                    flag_s[slot] = token;
                } else {
                    bestk_s[token] = k1;
                    iws[(size_t)m * NTOK + tok0 + token] = (float)k1;
                }
            }
        }
    }
    __syncthreads();

    // ---- pass 2: candidate-set rescan, one wave per 16 flagged tokens ----
    const int nflag = cnt_s;
    for (int g0 = w * 16; g0 < nflag; g0 += 64) {
        // A fragments for this group's tokens (load-mapping: row = ln15)
        const int slotL = g0 + ln15;
        const int tokL  = flag_s[slotL < nflag ? slotL : g0];
        bf16x8 fxh[2];
        #pragma unroll
        for (int c = 0; c < 2; ++c) {
            const float* src = emb + (size_t)(tok0 + tokL) * EMB + m * SDIM + c * 32 + q * 8;
            float4 v0 = *(const float4*)(src);
            float4 v1 = *(const float4*)(src + 4);
            float vv[8] = {v0.x,v0.y,v0.z,v0.w,v1.x,v1.y,v1.z,v1.w};
            #pragma unroll
            for (int j = 0; j < 8; ++j)
                fxh[c][j] = bf16rn(vv[j]);
        }

        // per-slot margins (token uniform across the ln15 group)
        float Mg[4];
        #pragma unroll
        for (int g = 0; g < 4; ++g) {
            const int slot = g0 + q * 4 + g;
            const int tokg = flag_s[slot < nflag ? slot : g0];
            Mg[g] = MCOEF * sqrtf(x2s[tokg] * c2mx) + MFLOOR;
        }

        // fast re-pass: collect candidate masks {k : s <= v1_run + M}
        unsigned long long cmask[4] = {0ull, 0ull, 0ull, 0ull};
        float v1r[4] = {3.4e38f, 3.4e38f, 3.4e38f, 3.4e38f};
        const unsigned short* bp0 = gB + (size_t)l * 8;
        bf16x8 Bc0 = *(const bf16x8*)(bp0);
        bf16x8 Bc1 = *(const bf16x8*)(bp0 + 512);
        #pragma unroll 2
        for (int tc = 0; tc < 64; ++tc) {
            bf16x8 Bn0, Bn1;
            if (tc < 63) {
                const unsigned short* bpn = gB + (size_t)(tc + 1) * 1024 + (size_t)l * 8;
                Bn0 = *(const bf16x8*)(bpn);
                Bn1 = *(const bf16x8*)(bpn + 512);
            }
            const int kk = tc * 16 + ln15;
            const float c2v = C2s[kk];
            f32x4 acc = {c2v, c2v, c2v, c2v};
            acc = __builtin_amdgcn_mfma_f32_16x16x32_bf16(fxh[0], Bc0, acc, 0, 0, 0);
            acc = __builtin_amdgcn_mfma_f32_16x16x32_bf16(fxh[1], Bc1, acc, 0, 0, 0);
            #pragma unroll
            for (int g = 0; g < 4; ++g) {
                float s = acc[g];
                bool cand = (s <= v1r[g] + Mg[g]);
                cmask[g] |= cand ? (1ull << tc) : 0ull;
                v1r[g] = fminf(v1r[g], s);
            }
            Bc0 = Bn0; Bc1 = Bn1;
        }

        // exact evaluation of candidates only (output-mapping: row = q*4+g)
        #pragma unroll
        for (int g = 0; g < 4; ++g) {
            const int slot = g0 + q * 4 + g;          // uniform across ln15 group
            if (slot < nflag) {
                const int token = flag_s[slot];
                const float* xrow = emb + (size_t)(tok0 + token) * EMB + m * SDIM;
                unsigned long long msk = cmask[g];
                const float x2v = np_sq64(xrow);
                float bv = 3.4e38f; int bk = CBK;
                while (msk) {
                    const int tc = __builtin_ctzll(msk);
                    msk &= msk - 1;                   // ascending tc -> ascending k
                    const int k = tc * 16 + ln15;
                    const float* crow = cb + ((size_t)m * CBK + k) * SDIM;
                    float acc = 0.f;
                    #pragma unroll
                    for (int i = 0; i < 16; ++i) {
                        float4 c4 = *(const float4*)(crow + 4 * i);
                        float4 x4 = *(const float4*)(xrow + 4 * i);
                        acc = __fmaf_rn(x4.x, c4.x, acc);
                        acc = __fmaf_rn(x4.y, c4.y, acc);
                        acc = __fmaf_rn(x4.z, c4.z, acc);
                        acc = __fmaf_rn(x4.w, c4.w, acc);
                    }
                    const float dist = fadd(fsub(x2v, fmul(2.f, acc)), C2s[k]);
                    if (dist < bv) { bv = dist; bk = k; }   // strict < keeps smallest k
                }
                // (val,k)-lexicographic min across the 16 lanes of this q-group
                #pragma unroll
                for (int mask = 1; mask < 16; mask <<= 1) {
                    float ov = __shfl_xor(bv, mask);
                    int   ok = __shfl_xor(bk, mask);
                    if (ov < bv || (ov == bv && ok < bk)) { bv = ov; bk = ok; }
                }
                if (ln15 == 0) {
                    bestk_s[token] = bk;
                    iws[(size_t)m * NTOK + tok0 + token] = (float)bk;
                }
            }
        }
    }
    __syncthreads();

    // ---- gather winning codewords ----
    {
        const int tok = t >> 1, d0 = (t & 1) * 32;
        const int bk  = bestk_s[tok];
        const float* src = cb + ((size_t)m * CBK + bk) * SDIM + d0;
        float* dst = qout + (size_t)(tok0 + tok) * EMB + m * SDIM + d0;
        #pragma unroll
        for (int i = 0; i < 8; ++i)
            *(float4*)(dst + 4 * i) = *(const float4*)(src + 4 * i);
    }
}

extern "C" void kernel_launch(void* const* d_in, const int* in_sizes, int n_in,
                              void* d_out, int out_size, void* d_ws, size_t ws_size,
                              hipStream_t stream) {
    const float* emb = (const float*)d_in[0];   // [8,2048,1024] f32
    const float* cb  = (const float*)d_in[1];   // [16,1024,64] f32
    float* qout = (float*)d_out;                              // [N, EMB] f32
    float* iout = (float*)d_out + (size_t)NTOK * EMB;         // [N, 16] as f32

    unsigned short* bpack = (unsigned short*)d_ws;            // 2 MB
    float* c2g = (float*)((char*)d_ws + 2u * 1024u * 1024u);  // 64 KB
    float* iws = (float*)((char*)d_ws + 2u * 1024u * 1024u + 64u * 1024u); // 1 MB

    prep_kernel<<<dim3(32, 16), 256, 0, stream>>>(cb, bpack, c2g);
    pq_mfma_kernel<<<dim3(NTOK / TOKB * NSUB), 256, 0, stream>>>(
        emb, cb, bpack, c2g, qout, iws);
    idx_transpose_kernel<<<dim3(NTOK / 256), 256, 0, stream>>>(iws, iout);
}